// Round 3
// baseline (2419.764 us; speedup 1.0000x reference)
//
#include <hip/hip_runtime.h>

#define NN    32768
#define NACT  28672
#define NPAD  4096
#define NEDGE 229376
#define NLAY  8

// packed weight layout: per layer, hi plane (69632 elems) then lo plane (69632)
#define WOFF_T0 0        // edge W1ext : KT=4 NT=9  (K=128 src|dst, N=144: ew1 + eresw cols)
#define WOFF_T1 18432    // mlp1 W1    : KT=2 NT=8  (K=64 src, N=128)
#define WOFF_T2 26624    // mlp1 W2ext : KT=4 NT=5  (K=128, N=80: 66 real)
#define WOFF_T3 36864    // node W1ext : KT=4 NT=12 (K=128 nodes|agg, N=192: w1 + res)
#define WOFF_T4 61440    // node W2    : KT=4 NT=4  (K=128, N=64)
#define WLO     69632
#define WLAYER  139264

typedef __attribute__((ext_vector_type(8))) short bf16x8;
typedef __attribute__((ext_vector_type(4))) float f32x4;

#define MFMA16(a,b,c) __builtin_amdgcn_mfma_f32_16x16x32_bf16((a),(b),(c),0,0,0)

__device__ __forceinline__ unsigned short f2bf(float f){
  union { float f; unsigned u; } v; v.f = f;
  unsigned r = v.u + 0x7fffu + ((v.u >> 16) & 1u);
  return (unsigned short)(r >> 16);
}
__device__ __forceinline__ float bf2f(unsigned short b){
  union { unsigned u; float f; } v; v.u = ((unsigned)b) << 16;
  return v.f;
}

// ---------------- weight packing (hi + lo planes) ----------------
__global__ void k_pack(const float* __restrict__ ew1, const float* __restrict__ eresw,
                       const float* __restrict__ n1w1, const float* __restrict__ n1w2,
                       const float* __restrict__ n2w1, const float* __restrict__ n2resw,
                       const float* __restrict__ n2w2,
                       unsigned short* __restrict__ wfrag){
  const int l = blockIdx.y, T = blockIdx.z;
  int KT, NT, off;
  if (T==0){ KT=4; NT=9;  off=WOFF_T0; }
  else if (T==1){ KT=2; NT=8;  off=WOFF_T1; }
  else if (T==2){ KT=4; NT=5;  off=WOFF_T2; }
  else if (T==3){ KT=4; NT=12; off=WOFF_T3; }
  else          { KT=4; NT=4;  off=WOFF_T4; }
  const int f = blockIdx.x*256 + threadIdx.x;
  if (f >= KT*NT*64) return;
  const int lane = f & 63;
  const int fn = f >> 6;
  const int nt = fn % NT, ks = fn / NT;
  const int n  = nt*16 + (lane & 15);
  const int kb = ks*32 + (lane >> 4)*8;
  bf16x8 vh, vl;
  #pragma unroll
  for (int i=0;i<8;++i){
    const int k = kb + i;
    float w = 0.f;
    if (T==0){
      if (n < 128)      w = ew1[((size_t)l*130 + k)*128 + n];
      else if (n < 130) w = eresw[((size_t)l*130 + k)*2 + (n-128)];
    } else if (T==1){
      w = n1w1[((size_t)l*66 + k)*128 + n];
    } else if (T==2){
      if (n < 66) w = n1w2[((size_t)l*128 + k)*66 + n];
    } else if (T==3){
      if (n < 128) w = n2w1[((size_t)l*130 + k)*128 + n];
      else         w = n2resw[((size_t)l*130 + k)*64 + (n-128)];
    } else {
      w = n2w2[((size_t)l*128 + k)*64 + n];
    }
    const unsigned short h = f2bf(w);
    vh[i] = (short)h;
    vl[i] = (short)f2bf(w - bf2f(h));
  }
  *(bf16x8*)(wfrag + (size_t)l*WLAYER + off + (size_t)f*8) = vh;
  *(bf16x8*)(wfrag + (size_t)l*WLAYER + off + WLO + (size_t)f*8) = vl;
}

// ---------------- init ----------------
__global__ void k_init(const float* __restrict__ x, const float* __restrict__ ea,
                       float* __restrict__ nodes, float* __restrict__ edges,
                       int* __restrict__ cnt){
  const int i = blockIdx.x*256 + threadIdx.x;   // grid = exactly NN*64
  nodes[i] = (i >= NPAD*64) ? x[i - NPAD*64] : 0.f;
  if (i < NEDGE*2) edges[i] = ea[i];
  if (i < NN) cnt[i] = 0;
}

__global__ void k_count(const int* __restrict__ ei, int* __restrict__ cnt){
  const int e = blockIdx.x*256 + threadIdx.x;
  if (e < NEDGE) atomicAdd(&cnt[ei[NEDGE + e]], 1);
}

__global__ void k_inv(const int* __restrict__ cnt, float* __restrict__ invc){
  const int n = blockIdx.x*256 + threadIdx.x;
  if (n < NN) invc[n] = 1.0f / (float)max(cnt[n], 1);
}

__global__ void k_zero_agg(float* __restrict__ agg){
  const int i = blockIdx.x*256 + threadIdx.x;   // grid exactly NN*66
  agg[i] = 0.f;
}

// split a fp32 8-vector into hi/lo bf16x8
__device__ __forceinline__ void split8(const float* v, bf16x8& h, bf16x8& l){
  #pragma unroll
  for (int i=0;i<8;++i){
    const unsigned short hh = f2bf(v[i]);
    h[i] = (short)hh;
    l[i] = (short)f2bf(v[i] - bf2f(hh));
  }
}

// ---------------- fused edge kernel: EdgeModel + NodeModel.mlp_1 + scatter ----------------
__global__ __launch_bounds__(256,2)
void k_edge(const int* __restrict__ ei, float* __restrict__ edges,
            const float* __restrict__ nodes,
            const unsigned short* __restrict__ wf,
            float* __restrict__ agg,
            const float* __restrict__ eb1, const float* __restrict__ ew2,
            const float* __restrict__ eb2, const float* __restrict__ eresb,
            const float* __restrict__ elng, const float* __restrict__ elnb,
            const float* __restrict__ ew1_tail,   // e_w1 rows 128,129 (stride 128)
            const float* __restrict__ eresw_tail, // e_res_w rows 128,129 (stride 2)
            const float* __restrict__ n1w1_tail,  // n1_w1 rows 64,65 (stride 128)
            const float* __restrict__ n1b1, const float* __restrict__ n1b2,
            const float* __restrict__ n1lng, const float* __restrict__ n1lnb)
{
  __shared__ __align__(16) unsigned char sAh[128*128];  // src hi
  __shared__ __align__(16) unsigned char sAl[128*128];  // src lo
  __shared__ __align__(16) unsigned char sBH[128*256];  // dst hi/lo; later H2 hi then H2 lo
  __shared__ float sEold[128][2];
  __shared__ int   sCol[128];

  const int tid = threadIdx.x;
  const int ebase = blockIdx.x * 128;

  { // staging (wave-uniform split: threads 0..127 src, 128..255 dst)
    const int r = tid & 127, h = tid >> 7;
    const int eidx = ebase + r;
    const int swz = (r & 7) << 4;
    if (h == 0){
      const int sn = ei[eidx];
      const float4* sp = (const float4*)(nodes + (size_t)sn*64);
      #pragma unroll
      for (int c = 0; c < 8; ++c){
        const float4 f0 = sp[2*c], f1 = sp[2*c+1];
        float v[8] = {f0.x,f0.y,f0.z,f0.w,f1.x,f1.y,f1.z,f1.w};
        bf16x8 hh, ll; split8(v, hh, ll);
        const int o = r*128 + ((c*16) ^ swz);
        *(bf16x8*)&sAh[o] = hh;
        *(bf16x8*)&sAl[o] = ll;
      }
    } else {
      const int dn = ei[NEDGE + eidx];
      const float4* dp = (const float4*)(nodes + (size_t)dn*64);
      #pragma unroll
      for (int c = 0; c < 8; ++c){
        const float4 f0 = dp[2*c], f1 = dp[2*c+1];
        float v[8] = {f0.x,f0.y,f0.z,f0.w,f1.x,f1.y,f1.z,f1.w};
        bf16x8 hh, ll; split8(v, hh, ll);
        const int o = r*128 + ((c*16) ^ swz);
        *(bf16x8*)&sBH[o] = hh;
        *(bf16x8*)&sBH[16384 + o] = ll;
      }
      const float2 ev = *(const float2*)(edges + (size_t)eidx*2);
      sEold[r][0] = ev.x; sEold[r][1] = ev.y;
      sCol[r] = dn;
    }
  }
  __syncthreads();

  const int lane  = tid & 63;
  const int wv    = tid >> 6;
  const int colj  = lane & 15;
  const int g     = lane >> 4;
  const int rowA0 = wv*32 + colj;      // A-frag row (rb=0)
  const int mrow0 = wv*32 + g*4;       // C/D row base (add rb*16 + r)

  // per-output-row old edge values (fp32)
  float e0r[2][4], e1r[2][4];
  #pragma unroll
  for (int rb=0; rb<2; ++rb)
    #pragma unroll
    for (int r=0; r<4; ++r){
      const int m = mrow0 + rb*16 + r;
      e0r[rb][r] = sEold[m][0]; e1r[rb][r] = sEold[m][1];
    }

  // ---- phase 1: Hext[128,144] = X[128,128] @ W1ext + e-cols fp32 rank-2 ----
  f32x4 acc1[9][2];
  #pragma unroll
  for (int i=0;i<9;++i){ acc1[i][0] = f32x4{0,0,0,0}; acc1[i][1] = f32x4{0,0,0,0}; }
  {
    #pragma unroll
    for (int ks = 0; ks < 4; ++ks){
      const int ch = (ks&1)*4 + g;
      const unsigned char* pH = (ks<2) ? sAh : sBH;
      const unsigned char* pL = (ks<2) ? sAl : (sBH + 16384);
      const int r1 = rowA0 + 16;
      const int o0 = rowA0*128 + ((ch*16) ^ ((rowA0&7)<<4));
      const int o1 = r1*128    + ((ch*16) ^ ((r1&7)<<4));
      const bf16x8 ah0 = *(const bf16x8*)&pH[o0];
      const bf16x8 ah1 = *(const bf16x8*)&pH[o1];
      const bf16x8 al0 = *(const bf16x8*)&pL[o0];
      const bf16x8 al1 = *(const bf16x8*)&pL[o1];
      const bf16x8* bh = (const bf16x8*)(wf + WOFF_T0) + (ks*9)*64 + lane;
      const bf16x8* bl = (const bf16x8*)(wf + WOFF_T0 + WLO) + (ks*9)*64 + lane;
      #pragma unroll
      for (int nt = 0; nt < 9; ++nt){
        const bf16x8 b = bh[nt*64];
        const bf16x8 bb = bl[nt*64];
        acc1[nt][0] = MFMA16(ah0, b,  acc1[nt][0]);
        acc1[nt][0] = MFMA16(al0, b,  acc1[nt][0]);
        acc1[nt][0] = MFMA16(ah0, bb, acc1[nt][0]);
        acc1[nt][1] = MFMA16(ah1, b,  acc1[nt][1]);
        acc1[nt][1] = MFMA16(al1, b,  acc1[nt][1]);
        acc1[nt][1] = MFMA16(ah1, bb, acc1[nt][1]);
      }
    }
    // e columns (W rows 128,129) exact in fp32
    #pragma unroll
    for (int nt=0; nt<9; ++nt){
      const int j = nt*16 + colj;
      float w0, w1;
      if (nt < 8){ w0 = ew1_tail[j]; w1 = ew1_tail[128 + j]; }
      else { w0 = (colj<2) ? eresw_tail[colj] : 0.f; w1 = (colj<2) ? eresw_tail[2+colj] : 0.f; }
      #pragma unroll
      for (int rb=0; rb<2; ++rb)
        #pragma unroll
        for (int r=0; r<4; ++r)
          acc1[nt][rb][r] += e0r[rb][r]*w0 + e1r[rb][r]*w1;
    }
  }

  // ---- phase 2: edge head (N=2) + LN(2) + residual ----
  float enew[2][4][2];
  {
    float2 w2v[8]; float b1v[8];
    #pragma unroll
    for (int nt=0; nt<8; ++nt){
      const int j = nt*16 + colj;
      w2v[nt] = *(const float2*)(ew2 + (size_t)j*2);
      b1v[nt] = eb1[j];
    }
    const float rb0 = eresb[0], rb1 = eresb[1];
    const float g0 = elng[0], g1 = elng[1], lb0 = elnb[0], lb1 = elnb[1];
    const float bb0 = eb2[0], bb1 = eb2[1];
    #pragma unroll
    for (int rb=0; rb<2; ++rb){
      #pragma unroll
      for (int r=0; r<4; ++r){
        float v0 = 0.f, v1 = 0.f;
        #pragma unroll
        for (int nt=0; nt<8; ++nt){
          const float h = fmaxf(acc1[nt][rb][r] + b1v[nt], 0.f);
          v0 = fmaf(h, w2v[nt].x, v0);
          v1 = fmaf(h, w2v[nt].y, v1);
        }
        const float resv = acc1[8][rb][r];
        if (colj == 0) v0 += resv + rb0;
        if (colj == 1) v1 += resv + rb1;
        #pragma unroll
        for (int mm=1; mm<16; mm<<=1){
          v0 += __shfl_xor(v0, mm, 64);
          v1 += __shfl_xor(v1, mm, 64);
        }
        v0 += bb0; v1 += bb1;
        const float s = 0.5f*(v0 - v1);
        const float iv = rsqrtf(s*s + 1e-5f);
        const int m = mrow0 + rb*16 + r;
        const float e0 = fmaf( s*iv, g0, lb0) + e0r[rb][r];
        const float e1 = fmaf(-s*iv, g1, lb1) + e1r[rb][r];
        enew[rb][r][0] = e0; enew[rb][r][1] = e1;
        if (colj == 0)
          *(float2*)(edges + (size_t)(ebase + m)*2) = make_float2(e0, e1);
      }
    }
  }

  // ---- phase 3: H2[128,128] = src[128,64] @ n1_w1 (+ fp32 rank-2 for e) ----
  f32x4 acc2[8][2];
  #pragma unroll
  for (int i=0;i<8;++i){ acc2[i][0] = f32x4{0,0,0,0}; acc2[i][1] = f32x4{0,0,0,0}; }
  #pragma unroll
  for (int ks=0; ks<2; ++ks){
    const int ch = ks*4 + g;
    const int r1 = rowA0 + 16;
    const int o0 = rowA0*128 + ((ch*16) ^ ((rowA0&7)<<4));
    const int o1 = r1*128    + ((ch*16) ^ ((r1&7)<<4));
    const bf16x8 ah0 = *(const bf16x8*)&sAh[o0];
    const bf16x8 ah1 = *(const bf16x8*)&sAh[o1];
    const bf16x8 al0 = *(const bf16x8*)&sAl[o0];
    const bf16x8 al1 = *(const bf16x8*)&sAl[o1];
    const bf16x8* bh = (const bf16x8*)(wf + WOFF_T1) + (ks*8)*64 + lane;
    const bf16x8* bl = (const bf16x8*)(wf + WOFF_T1 + WLO) + (ks*8)*64 + lane;
    #pragma unroll
    for (int nt = 0; nt < 8; ++nt){
      const bf16x8 b = bh[nt*64];
      const bf16x8 bb = bl[nt*64];
      acc2[nt][0] = MFMA16(ah0, b,  acc2[nt][0]);
      acc2[nt][0] = MFMA16(al0, b,  acc2[nt][0]);
      acc2[nt][0] = MFMA16(ah0, bb, acc2[nt][0]);
      acc2[nt][1] = MFMA16(ah1, b,  acc2[nt][1]);
      acc2[nt][1] = MFMA16(al1, b,  acc2[nt][1]);
      acc2[nt][1] = MFMA16(ah1, bb, acc2[nt][1]);
    }
  }
  {
    #pragma unroll
    for (int nt=0; nt<8; ++nt){
      const int j = nt*16 + colj;
      const float w64 = n1w1_tail[j];
      const float w65 = n1w1_tail[128 + j];
      #pragma unroll
      for (int rb=0; rb<2; ++rb)
        #pragma unroll
        for (int r=0; r<4; ++r)
          acc2[nt][rb][r] += enew[rb][r][0]*w64 + enew[rb][r][1]*w65;
    }
  }
  { // add bias now so the LDS round-trip sees final hidden values
    #pragma unroll
    for (int nt=0; nt<8; ++nt){
      const float bb = n1b1[nt*16 + colj];
      #pragma unroll
      for (int rb=0; rb<2; ++rb)
        #pragma unroll
        for (int r=0; r<4; ++r)
          acc2[nt][rb][r] = fmaxf(acc2[nt][rb][r] + bb, 0.f);
    }
  }

  __syncthreads();   // all phase-1 reads of sBH done before overwrite

  // ---- phase 4a: H2 hi -> LDS bf16 (256B rows over sBH) ----
  {
    #pragma unroll
    for (int nt=0; nt<8; ++nt){
      const int j = nt*16 + colj;
      const int co = (j>>3)<<4, wi = (j&7)*2;
      #pragma unroll
      for (int rb=0; rb<2; ++rb)
        #pragma unroll
        for (int r=0; r<4; ++r){
          const int m = mrow0 + rb*16 + r;
          *(unsigned short*)&sBH[m*256 + ((co ^ ((m&7)<<4)) + wi)] = f2bf(acc2[nt][rb][r]);
        }
    }
  }
  __syncthreads();

  // ---- phase 4b-hi: acc3 += H2hi@Whi + H2hi@Wlo ----
  f32x4 acc3[5][2];
  #pragma unroll
  for (int i=0;i<5;++i){ acc3[i][0] = f32x4{0,0,0,0}; acc3[i][1] = f32x4{0,0,0,0}; }
  #pragma unroll
  for (int ks=0; ks<4; ++ks){
    const int ch = ks*4 + g;
    const int r1 = rowA0 + 16;
    const bf16x8 a0 = *(const bf16x8*)&sBH[rowA0*256 + ((ch*16) ^ ((rowA0&7)<<4))];
    const bf16x8 a1 = *(const bf16x8*)&sBH[r1*256    + ((ch*16) ^ ((r1&7)<<4))];
    const bf16x8* bh = (const bf16x8*)(wf + WOFF_T2) + (ks*5)*64 + lane;
    const bf16x8* bl = (const bf16x8*)(wf + WOFF_T2 + WLO) + (ks*5)*64 + lane;
    #pragma unroll
    for (int nt = 0; nt < 5; ++nt){
      const bf16x8 b = bh[nt*64];
      const bf16x8 bb = bl[nt*64];
      acc3[nt][0] = MFMA16(a0, b,  acc3[nt][0]);
      acc3[nt][0] = MFMA16(a0, bb, acc3[nt][0]);
      acc3[nt][1] = MFMA16(a1, b,  acc3[nt][1]);
      acc3[nt][1] = MFMA16(a1, bb, acc3[nt][1]);
    }
  }
  __syncthreads();

  // ---- phase 4a': H2 lo -> LDS ----
  {
    #pragma unroll
    for (int nt=0; nt<8; ++nt){
      const int j = nt*16 + colj;
      const int co = (j>>3)<<4, wi = (j&7)*2;
      #pragma unroll
      for (int rb=0; rb<2; ++rb)
        #pragma unroll
        for (int r=0; r<4; ++r){
          const int m = mrow0 + rb*16 + r;
          const float h = acc2[nt][rb][r];
          *(unsigned short*)&sBH[m*256 + ((co ^ ((m&7)<<4)) + wi)] = f2bf(h - bf2f(f2bf(h)));
        }
    }
  }
  __syncthreads();

  // ---- phase 4b-lo: acc3 += H2lo@Whi ----
  #pragma unroll
  for (int ks=0; ks<4; ++ks){
    const int ch = ks*4 + g;
    const int r1 = rowA0 + 16;
    const bf16x8 a0 = *(const bf16x8*)&sBH[rowA0*256 + ((ch*16) ^ ((rowA0&7)<<4))];
    const bf16x8 a1 = *(const bf16x8*)&sBH[r1*256    + ((ch*16) ^ ((r1&7)<<4))];
    const bf16x8* bh = (const bf16x8*)(wf + WOFF_T2) + (ks*5)*64 + lane;
    #pragma unroll
    for (int nt = 0; nt < 5; ++nt){
      const bf16x8 b = bh[nt*64];
      acc3[nt][0] = MFMA16(a0, b, acc3[nt][0]);
      acc3[nt][1] = MFMA16(a1, b, acc3[nt][1]);
    }
  }

  // ---- phase 4c: LN(66) + scatter-add ----
  {
    float b2v[5], lgv[5], lbv[5];
    #pragma unroll
    for (int nt=0; nt<5; ++nt){
      const int j = nt*16 + colj;
      const bool ok = j < 66;
      b2v[nt] = ok ? n1b2[j]  : 0.f;
      lgv[nt] = ok ? n1lng[j] : 0.f;
      lbv[nt] = ok ? n1lnb[j] : 0.f;
    }
    #pragma unroll
    for (int rb=0; rb<2; ++rb){
      #pragma unroll
      for (int r=0; r<4; ++r){
        const int m = mrow0 + rb*16 + r;
        float v[5]; float sum = 0.f, sq = 0.f;
        #pragma unroll
        for (int nt=0; nt<5; ++nt){
          const int j = nt*16 + colj;
          float xv = 0.f;
          if (j < 64){
            const int o = m*128 + (((((j>>3)<<4)) ^ ((m&7)<<4)) + (j&7)*2);
            const float resd = bf2f(*(const unsigned short*)&sAh[o])
                             + bf2f(*(const unsigned short*)&sAl[o]);
            xv = acc3[nt][rb][r] + b2v[nt] + resd;
          } else if (j < 66){
            xv = acc3[nt][rb][r] + b2v[nt] + enew[rb][r][j-64];
          }
          v[nt] = xv;
          sum += xv; sq += xv*xv;
        }
        #pragma unroll
        for (int mm=1; mm<16; mm<<=1){
          sum += __shfl_xor(sum, mm, 64);
          sq  += __shfl_xor(sq,  mm, 64);
        }
        const float mean = sum * (1.f/66.f);
        const float var  = sq  * (1.f/66.f) - mean*mean;
        const float rstd = rsqrtf(var + 1e-5f);
        float* arow = agg + (size_t)sCol[m]*66;
        #pragma unroll
        for (int nt=0; nt<5; ++nt){
          const int j = nt*16 + colj;
          if (j < 66){
            const float o = fmaf((v[nt]-mean)*rstd, lgv[nt], lbv[nt]);
            atomicAdd(arow + j, o);
          }
        }
      }
    }
  }
}

// ---------------- node kernel: NodeModel.mlp_2 ----------------
__global__ __launch_bounds__(256,2)
void k_node(float* __restrict__ nodes,
            const float* __restrict__ agg, const float* __restrict__ invc,
            const unsigned short* __restrict__ wf,
            const float* __restrict__ b1, const float* __restrict__ resb,
            const float* __restrict__ b2, const float* __restrict__ lng,
            const float* __restrict__ lnb,
            const float* __restrict__ n2w1_tail,   // n2_w1 rows 128,129 (stride 128)
            const float* __restrict__ n2resw_tail) // n2_res_w rows 128,129 (stride 64)
{
  __shared__ __align__(16) unsigned char sAh[128*128];  // nodes hi
  __shared__ __align__(16) unsigned char sAl[128*128];  // nodes lo
  __shared__ __align__(16) unsigned char sBH[128*256];  // agg hi/lo; later H3 hi then lo
  __shared__ float sAgg2[128][2];

  const int tid = threadIdx.x;
  const int nbase = blockIdx.x * 128;

  { // staging
    const int r = tid & 127, h = tid >> 7;
    const int node = nbase + r;
    const int swz = (r & 7) << 4;
    if (h == 0){
      const float4* sp = (const float4*)(nodes + (size_t)node*64);
      #pragma unroll
      for (int c = 0; c < 8; ++c){
        const float4 f0 = sp[2*c], f1 = sp[2*c+1];
        float v[8] = {f0.x,f0.y,f0.z,f0.w,f1.x,f1.y,f1.z,f1.w};
        bf16x8 hh, ll; split8(v, hh, ll);
        const int o = r*128 + ((c*16) ^ swz);
        *(bf16x8*)&sAh[o] = hh;
        *(bf16x8*)&sAl[o] = ll;
      }
    } else {
      const float iv = invc[node];
      const float* ar = agg + (size_t)node*66;
      #pragma unroll
      for (int c = 0; c < 8; ++c){
        float v[8];
        #pragma unroll
        for (int i=0;i<8;++i) v[i] = ar[c*8+i]*iv;
        bf16x8 hh, ll; split8(v, hh, ll);
        const int o = r*128 + ((c*16) ^ swz);
        *(bf16x8*)&sBH[o] = hh;
        *(bf16x8*)&sBH[16384 + o] = ll;
      }
      sAgg2[r][0] = ar[64]*iv; sAgg2[r][1] = ar[65]*iv;
    }
  }
  __syncthreads();

  const int lane  = tid & 63;
  const int wv    = tid >> 6;
  const int colj  = lane & 15;
  const int g     = lane >> 4;
  const int rowA0 = wv*32 + colj;
  const int mrow0 = wv*32 + g*4;

  float a0r[2][4], a1r[2][4];
  #pragma unroll
  for (int rb=0; rb<2; ++rb)
    #pragma unroll
    for (int r=0; r<4; ++r){
      const int m = mrow0 + rb*16 + r;
      a0r[rb][r] = sAgg2[m][0]; a1r[rb][r] = sAgg2[m][1];
    }

  // ---- GEMM1: [128,128] @ W1ext -> [128,192] (+ agg-tail fp32 rank-2) ----
  f32x4 acc1[12][2];
  #pragma unroll
  for (int i=0;i<12;++i){ acc1[i][0] = f32x4{0,0,0,0}; acc1[i][1] = f32x4{0,0,0,0}; }
  #pragma unroll
  for (int ks = 0; ks < 4; ++ks){
    const int ch = (ks&1)*4 + g;
    const unsigned char* pH = (ks<2) ? sAh : sBH;
    const unsigned char* pL = (ks<2) ? sAl : (sBH + 16384);
    const int r1 = rowA0 + 16;
    const int o0 = rowA0*128 + ((ch*16) ^ ((rowA0&7)<<4));
    const int o1 = r1*128    + ((ch*16) ^ ((r1&7)<<4));
    const bf16x8 ah0 = *(const bf16x8*)&pH[o0];
    const bf16x8 ah1 = *(const bf16x8*)&pH[o1];
    const bf16x8 al0 = *(const bf16x8*)&pL[o0];
    const bf16x8 al1 = *(const bf16x8*)&pL[o1];
    const bf16x8* bh = (const bf16x8*)(wf + WOFF_T3) + (ks*12)*64 + lane;
    const bf16x8* bl = (const bf16x8*)(wf + WOFF_T3 + WLO) + (ks*12)*64 + lane;
    #pragma unroll
    for (int nt = 0; nt < 12; ++nt){
      const bf16x8 b = bh[nt*64];
      const bf16x8 bb = bl[nt*64];
      acc1[nt][0] = MFMA16(ah0, b,  acc1[nt][0]);
      acc1[nt][0] = MFMA16(al0, b,  acc1[nt][0]);
      acc1[nt][0] = MFMA16(ah0, bb, acc1[nt][0]);
      acc1[nt][1] = MFMA16(ah1, b,  acc1[nt][1]);
      acc1[nt][1] = MFMA16(al1, b,  acc1[nt][1]);
      acc1[nt][1] = MFMA16(ah1, bb, acc1[nt][1]);
    }
  }
  { // agg cols 64,65 (W rows 128,129) exact fp32
    #pragma unroll
    for (int nt=0; nt<12; ++nt){
      const int j = nt*16 + colj;
      float w0, w1;
      if (j < 128){ w0 = n2w1_tail[j]; w1 = n2w1_tail[128 + j]; }
      else { w0 = n2resw_tail[j-128]; w1 = n2resw_tail[64 + (j-128)]; }
      #pragma unroll
      for (int rb=0; rb<2; ++rb)
        #pragma unroll
        for (int r=0; r<4; ++r)
          acc1[nt][rb][r] += a0r[rb][r]*w0 + a1r[rb][r]*w1;
    }
  }
  { // fold bias+relu into acc1 hidden part
    #pragma unroll
    for (int nt=0; nt<8; ++nt){
      const float bb = b1[nt*16 + colj];
      #pragma unroll
      for (int rb=0; rb<2; ++rb)
        #pragma unroll
        for (int r=0; r<4; ++r)
          acc1[nt][rb][r] = fmaxf(acc1[nt][rb][r] + bb, 0.f);
    }
  }

  __syncthreads();   // all reads of sBH done before overwrite with H3

  { // H3 hi -> LDS (256B rows)
    #pragma unroll
    for (int nt=0; nt<8; ++nt){
      const int j = nt*16 + colj;
      const int co = (j>>3)<<4, wi = (j&7)*2;
      #pragma unroll
      for (int rb=0; rb<2; ++rb)
        #pragma unroll
        for (int r=0; r<4; ++r){
          const int m = mrow0 + rb*16 + r;
          *(unsigned short*)&sBH[m*256 + ((co ^ ((m&7)<<4)) + wi)] = f2bf(acc1[nt][rb][r]);
        }
    }
  }
  __syncthreads();

  // ---- GEMM2-hi: acc2 += H3hi@Whi + H3hi@Wlo ----
  f32x4 acc2[4][2];
  #pragma unroll
  for (int i=0;i<4;++i){ acc2[i][0] = f32x4{0,0,0,0}; acc2[i][1] = f32x4{0,0,0,0}; }
  #pragma unroll
  for (int ks=0; ks<4; ++ks){
    const int ch = ks*4 + g;
    const int r1 = rowA0 + 16;
    const bf16x8 a0 = *(const bf16x8*)&sBH[rowA0*256 + ((ch*16) ^ ((rowA0&7)<<4))];
    const bf16x8 a1 = *(const bf16x8*)&sBH[r1*256    + ((ch*16) ^ ((r1&7)<<4))];
    const bf16x8* bh = (const bf16x8*)(wf + WOFF_T4) + (ks*4)*64 + lane;
    const bf16x8* bl = (const bf16x8*)(wf + WOFF_T4 + WLO) + (ks*4)*64 + lane;
    #pragma unroll
    for (int nt = 0; nt < 4; ++nt){
      const bf16x8 b = bh[nt*64];
      const bf16x8 bb = bl[nt*64];
      acc2[nt][0] = MFMA16(a0, b,  acc2[nt][0]);
      acc2[nt][0] = MFMA16(a0, bb, acc2[nt][0]);
      acc2[nt][1] = MFMA16(a1, b,  acc2[nt][1]);
      acc2[nt][1] = MFMA16(a1, bb, acc2[nt][1]);
    }
  }
  __syncthreads();

  { // H3 lo -> LDS
    #pragma unroll
    for (int nt=0; nt<8; ++nt){
      const int j = nt*16 + colj;
      const int co = (j>>3)<<4, wi = (j&7)*2;
      #pragma unroll
      for (int rb=0; rb<2; ++rb)
        #pragma unroll
        for (int r=0; r<4; ++r){
          const int m = mrow0 + rb*16 + r;
          const float h = acc1[nt][rb][r];
          *(unsigned short*)&sBH[m*256 + ((co ^ ((m&7)<<4)) + wi)] = f2bf(h - bf2f(f2bf(h)));
        }
    }
  }
  __syncthreads();

  // ---- GEMM2-lo: acc2 += H3lo@Whi ----
  #pragma unroll
  for (int ks=0; ks<4; ++ks){
    const int ch = ks*4 + g;
    const int r1 = rowA0 + 16;
    const bf16x8 a0 = *(const bf16x8*)&sBH[rowA0*256 + ((ch*16) ^ ((rowA0&7)<<4))];
    const bf16x8 a1 = *(const bf16x8*)&sBH[r1*256    + ((ch*16) ^ ((r1&7)<<4))];
    const bf16x8* bh = (const bf16x8*)(wf + WOFF_T4) + (ks*4)*64 + lane;
    #pragma unroll
    for (int nt = 0; nt < 4; ++nt){
      const bf16x8 b = bh[nt*64];
      acc2[nt][0] = MFMA16(a0, b, acc2[nt][0]);
      acc2[nt][1] = MFMA16(a1, b, acc2[nt][1]);
    }
  }

  // ---- epilogue: LN(64) + residual + "+nodes" ----
  {
    float b2v[4], rbv[4], lgv[4], lbv[4];
    #pragma unroll
    for (int nt=0; nt<4; ++nt){
      const int j = nt*16 + colj;
      b2v[nt] = b2[j]; rbv[nt] = resb[j]; lgv[nt] = lng[j]; lbv[nt] = lnb[j];
    }
    #pragma unroll
    for (int rb=0; rb<2; ++rb){
      #pragma unroll
      for (int r=0; r<4; ++r){
        const int m = mrow0 + rb*16 + r;
        const int node = nbase + m;
        float v[4]; float sum = 0.f, sq = 0.f;
        #pragma unroll
        for (int nt=0; nt<4; ++nt){
          const float xv = acc2[nt][rb][r] + b2v[nt] + acc1[8+nt][rb][r] + rbv[nt];
          v[nt] = xv; sum += xv; sq += xv*xv;
        }
        #pragma unroll
        for (int mm=1; mm<16; mm<<=1){
          sum += __shfl_xor(sum, mm, 64);
          sq  += __shfl_xor(sq,  mm, 64);
        }
        const float mean = sum * (1.f/64.f);
        const float var  = sq  * (1.f/64.f) - mean*mean;
        const float rstd = rsqrtf(var + 1e-5f);
        #pragma unroll
        for (int nt=0; nt<4; ++nt){
          const int j = nt*16 + colj;
          const size_t idx = (size_t)node*64 + j;
          nodes[idx] = fmaf((v[nt]-mean)*rstd, lgv[nt], lbv[nt]) + nodes[idx];
        }
      }
    }
  }
}

__global__ void k_copy(const float* __restrict__ nodes, float* __restrict__ out){
  const int i = blockIdx.x*256 + threadIdx.x;   // grid exactly NACT*16
  if (i < NACT*16)
    ((float4*)out)[i] = ((const float4*)nodes)[NPAD*16 + i];
}

extern "C" void kernel_launch(void* const* d_in, const int* in_sizes, int n_in,
                              void* d_out, int out_size, void* d_ws, size_t ws_size,
                              hipStream_t stream){
  const float* x       = (const float*)d_in[0];
  const int*   ei      = (const int*)  d_in[1];
  const float* eattr   = (const float*)d_in[2];
  const float* e_res_w = (const float*)d_in[3];
  const float* e_res_b = (const float*)d_in[4];
  const float* e_w1    = (const float*)d_in[5];
  const float* e_b1    = (const float*)d_in[6];
  const float* e_w2    = (const float*)d_in[7];
  const float* e_b2    = (const float*)d_in[8];
  const float* e_ln_g  = (const float*)d_in[9];
  const float* e_ln_b  = (const float*)d_in[10];
  const float* n1_w1   = (const float*)d_in[11];
  const float* n1_b1   = (const float*)d_in[12];
  const float* n1_w2   = (const float*)d_in[13];
  const float* n1_b2   = (const float*)d_in[14];
  const float* n1_ln_g = (const float*)d_in[15];
  const float* n1_ln_b = (const float*)d_in[16];
  const float* n2_res_w= (const float*)d_in[17];
  const float* n2_res_b= (const float*)d_in[18];
  const float* n2_w1   = (const float*)d_in[19];
  const float* n2_b1   = (const float*)d_in[20];
  const float* n2_w2   = (const float*)d_in[21];
  const float* n2_b2   = (const float*)d_in[22];
  const float* n2_ln_g = (const float*)d_in[23];
  const float* n2_ln_b = (const float*)d_in[24];

  if (ws_size < 21364736u) return;

  char* ws = (char*)d_ws;
  float*          nodes = (float*)(ws + 0);             // NN*64 f32
  float*          edges = (float*)(ws + 8388608);       // NEDGE*2 f32
  float*          agg   = (float*)(ws + 10223616);      // NN*66 f32
  int*            cnt   = (int*)(ws + 18874368);
  float*          invc  = (float*)(ws + 19005440);
  unsigned short* wfrag = (unsigned short*)(ws + 19136512);

  k_pack<<<dim3(12,8,5),256,0,stream>>>(e_w1, e_res_w, n1_w1, n1_w2, n2_w1, n2_res_w, n2_w2, wfrag);
  k_init<<<8192,256,0,stream>>>(x, eattr, nodes, edges, cnt);
  k_count<<<896,256,0,stream>>>(ei, cnt);
  k_inv<<<128,256,0,stream>>>(cnt, invc);

  for (int l = 0; l < NLAY; ++l){
    k_zero_agg<<<8448,256,0,stream>>>(agg);
    k_edge<<<1792,256,0,stream>>>(ei, edges, nodes,
        wfrag + (size_t)l*WLAYER, agg,
        e_b1 + l*128, e_w2 + l*256, e_b2 + l*2, e_res_b + l*2, e_ln_g + l*2, e_ln_b + l*2,
        e_w1 + ((size_t)l*130 + 128)*128,
        e_res_w + ((size_t)l*130 + 128)*2,
        n1_w1 + ((size_t)l*66 + 64)*128,
        n1_b1 + l*128, n1_b2 + l*66, n1_ln_g + l*66, n1_ln_b + l*66);
    k_node<<<256,256,0,stream>>>(nodes, agg, invc,
        wfrag + (size_t)l*WLAYER,
        n2_b1 + l*128, n2_res_b + l*64, n2_b2 + l*64, n2_ln_g + l*64, n2_ln_b + l*64,
        n2_w1 + ((size_t)l*130 + 128)*128,
        n2_res_w + ((size_t)l*130 + 128)*64);
  }
  k_copy<<<1792,256,0,stream>>>(nodes, (float*)d_out);
}